// Round 1
// baseline (822.311 us; speedup 1.0000x reference)
//
#include <hip/hip_runtime.h>
#include <hip/hip_bf16.h>
#include <math.h>

// MoE: B=8,N=1024,E=1024,H=1536,X=8,K=2. Routed (top-2 only) bf16 MFMA impl.
#define T_TOK 8192
#define E_DIM 1024
#define H_DIM 1536
#define X_EXP 8

typedef unsigned short u16;
typedef unsigned int u32;

typedef __attribute__((ext_vector_type(8))) short frag_ab;   // 8 bf16 (4 VGPRs)
typedef __attribute__((ext_vector_type(4))) float frag_cd;   // 4 fp32 acc

__device__ __forceinline__ u16 f2bf(float f) {
  u32 u = __float_as_uint(f);
  u32 r = u + 0x7fffu + ((u >> 16) & 1u);   // round-to-nearest-even
  return (u16)(r >> 16);
}

__device__ __forceinline__ void gl2lds16(const u16* g, u16* l) {
  // async global->LDS, 16B per lane; LDS dst must be wave-uniform base + lane*16
  __builtin_amdgcn_global_load_lds((const __attribute__((address_space(1))) void*)g,
                                   (__attribute__((address_space(3))) void*)l,
                                   16, 0, 0);
}

// ---- workspace layout (bytes) ----
// meta ints: counts[8]@0, cursors[8]@64, offsets[8]@128
static const size_t O_T2    = 4096;                                   // T*2 ints
static const size_t O_CLIST = O_T2 + (size_t)T_TOK * 2 * 4;           // 69632
static const size_t O_XB    = O_CLIST + (size_t)T_TOK * 2 * 4;        // 135168
static const size_t O_W1T   = O_XB + (size_t)T_TOK * E_DIM * 2;       // 16912384
static const size_t O_W2T   = O_W1T + (size_t)X_EXP * E_DIM * H_DIM * 2; // 42078208
static const size_t O_HB    = O_W2T + (size_t)X_EXP * E_DIM * H_DIM * 2; // 67244032
// end = O_HB + 16384*1536*2 = 117575680 bytes (~112 MiB)

// ---- router: one wave per token, top-2 of logits (softmax monotonic) ----
__global__ __launch_bounds__(256) void k_router(const float* __restrict__ x,
                                                const float* __restrict__ Wr,
                                                const float* __restrict__ br,
                                                float* __restrict__ out,
                                                int* __restrict__ t2,
                                                int* __restrict__ counts) {
  int tid = threadIdx.x;
  int lane = tid & 63;
  int wave = tid >> 6;
  int t = blockIdx.x * 4 + wave;
  float acc[8];
#pragma unroll
  for (int e = 0; e < 8; e++) acc[e] = 0.f;
  const float* xr = x + (size_t)t * E_DIM;
  for (int i = lane; i < E_DIM; i += 64) {
    float xv = xr[i];
    const float* wr = Wr + (size_t)i * 8;
#pragma unroll
    for (int e = 0; e < 8; e++) acc[e] += xv * wr[e];
  }
#pragma unroll
  for (int off = 32; off; off >>= 1) {
#pragma unroll
    for (int e = 0; e < 8; e++) acc[e] += __shfl_down(acc[e], off);
  }
  if (lane == 0) {
    float lg[8];
#pragma unroll
    for (int e = 0; e < 8; e++) lg[e] = acc[e] + br[e];
    int i0 = 0; float v0 = lg[0];
#pragma unroll
    for (int e = 1; e < 8; e++) if (lg[e] > v0) { v0 = lg[e]; i0 = e; }
    int i1 = -1; float v1 = -3.4e38f;
#pragma unroll
    for (int e = 0; e < 8; e++) if (e != i0 && lg[e] > v1) { v1 = lg[e]; i1 = e; }
    // output tail: topk_idx as float (whole out buffer read as fp32 by harness)
    out[(size_t)T_TOK * E_DIM + (size_t)t * 2 + 0] = (float)i0;
    out[(size_t)T_TOK * E_DIM + (size_t)t * 2 + 1] = (float)i1;
    t2[t * 2 + 0] = i0;
    t2[t * 2 + 1] = i1;
    atomicAdd(&counts[i0], 1);
    atomicAdd(&counts[i1], 1);
  }
}

__global__ void k_scan(int* __restrict__ meta) {
  if (threadIdx.x == 0) {
    int run = 0;
    for (int e = 0; e < 8; e++) {
      meta[32 + e] = run;      // offsets
      run += meta[e];          // counts
      meta[16 + e] = 0;        // cursors
    }
  }
}

__global__ __launch_bounds__(256) void k_fill(const int* __restrict__ t2,
                                              int* __restrict__ curs,
                                              const int* __restrict__ offs,
                                              int* __restrict__ clist) {
  int t = blockIdx.x * 256 + threadIdx.x;
#pragma unroll
  for (int k = 0; k < 2; k++) {
    int e = t2[t * 2 + k];
    int p = atomicAdd(&curs[e], 1);
    clist[offs[e] + p] = t;
  }
}

// ---- convert x -> bf16 ----
__global__ __launch_bounds__(256) void k_convx(const float* __restrict__ src,
                                               u16* __restrict__ dst) {
  size_t i = ((size_t)blockIdx.x * 256 + threadIdx.x) * 4;
  float4 v = *(const float4*)(src + i);
  ushort4 o;
  o.x = f2bf(v.x); o.y = f2bf(v.y); o.z = f2bf(v.z); o.w = f2bf(v.w);
  *(ushort4*)(dst + i) = o;
}

// ---- per-expert transpose+convert: src[R][C] fp32 -> dst[C][R] bf16 ----
__global__ __launch_bounds__(256) void k_tconv(const float* __restrict__ src,
                                               u16* __restrict__ dst,
                                               int R, int C) {
  __shared__ float tile[32][33];
  int e = blockIdx.z;
  const float* s = src + (size_t)e * R * C;
  u16* d = dst + (size_t)e * R * C;
  int c0 = blockIdx.x * 32, r0 = blockIdx.y * 32;
  int tc = threadIdx.x & 31, tr = threadIdx.x >> 5;  // tr in 0..7
#pragma unroll
  for (int i = 0; i < 4; i++)
    tile[tr + i * 8][tc] = s[(size_t)(r0 + tr + i * 8) * C + c0 + tc];
  __syncthreads();
#pragma unroll
  for (int i = 0; i < 4; i++)
    d[(size_t)(c0 + tr + i * 8) * R + r0 + tc] = f2bf(tile[tc][tr + i * 8]);
}

// ---- GEMM1: h = gelu(gather(x) @ W1[e] + b1[e]) -> hb (bf16, compact rows) ----
// A: xb rows via clist (M=count[e], K=E). B: W1T[e] = [H][E] (N-major). Tile 128x128.
__global__ __launch_bounds__(256) void k_gemm1(const u16* __restrict__ xb,
                                               const u16* __restrict__ w1t,
                                               const float* __restrict__ b1,
                                               u16* __restrict__ hb,
                                               const int* __restrict__ counts,
                                               const int* __restrict__ offs,
                                               const int* __restrict__ clist) {
  int e = blockIdx.z;
  int cnt = counts[e];
  int m0 = blockIdx.x * 128;
  if (m0 >= cnt) return;
  int off = offs[e];
  int n0 = blockIdx.y * 128;
  int tid = threadIdx.x;
  int lane = tid & 63, wave = tid >> 6;
  int wm = wave >> 1, wn = wave & 1;

  __shared__ __align__(16) u16 lA[128 * 32];
  __shared__ __align__(16) u16 lB[128 * 32];

  const u16* gA[2];
  const u16* gB[2];
  int c = tid & 3;
#pragma unroll
  for (int s = 0; s < 2; s++) {
    int idx = s * 256 + tid;
    int r = idx >> 2;                       // 0..127
    int mrow = m0 + r; if (mrow >= cnt) mrow = cnt - 1;  // clamp tail (masked at store)
    int tok = clist[off + mrow];
    gA[s] = xb + (size_t)tok * E_DIM + c * 8;
    gB[s] = w1t + (size_t)e * H_DIM * E_DIM + (size_t)(n0 + r) * E_DIM + c * 8;
  }

  frag_cd acc[4][4] = {};
  int q = lane >> 4, mr = lane & 15;

  for (int k0 = 0; k0 < E_DIM; k0 += 32) {
#pragma unroll
    for (int s = 0; s < 2; s++) {
      gl2lds16(gA[s] + k0, lA + (size_t)(s * 256 + tid) * 8);
      gl2lds16(gB[s] + k0, lB + (size_t)(s * 256 + tid) * 8);
    }
    __syncthreads();   // drains vmcnt (compiler-inserted) before use
    frag_ab af[4], bfr[4];
#pragma unroll
    for (int i = 0; i < 4; i++)
      af[i] = *(const frag_ab*)(lA + (size_t)(wm * 64 + i * 16 + mr) * 32 + q * 8);
#pragma unroll
    for (int j = 0; j < 4; j++)
      bfr[j] = *(const frag_ab*)(lB + (size_t)(wn * 64 + j * 16 + mr) * 32 + q * 8);
#pragma unroll
    for (int i = 0; i < 4; i++)
#pragma unroll
      for (int j = 0; j < 4; j++)
        acc[i][j] = __builtin_amdgcn_mfma_f32_16x16x32_bf16(af[i], bfr[j], acc[i][j], 0, 0, 0);
    __syncthreads();
  }

  // epilogue: D[row=q*4+r][col=lane&15] per 16x16 tile
  int col = lane & 15;
#pragma unroll
  for (int i = 0; i < 4; i++) {
#pragma unroll
    for (int j = 0; j < 4; j++) {
#pragma unroll
      for (int r = 0; r < 4; r++) {
        int mg = m0 + wm * 64 + i * 16 + q * 4 + r;
        if (mg < cnt) {
          int ng = n0 + wn * 64 + j * 16 + col;
          float v = acc[i][j][r] + b1[e * H_DIM + ng];
          v = 0.5f * v * (1.0f + erff(v * 0.70710678118654752f));   // exact GELU
          hb[(size_t)(off + mg) * H_DIM + ng] = f2bf(v);
        }
      }
    }
  }
}

// ---- GEMM2: out[t] += 0.5*(hb @ W2[e] + b2[e]) ----
// A: hb compact rows (K=H). B: W2T[e] = [E][H]. Scatter via fp32 atomicAdd.
__global__ __launch_bounds__(256) void k_gemm2(const u16* __restrict__ hb,
                                               const u16* __restrict__ w2t,
                                               const float* __restrict__ b2,
                                               float* __restrict__ out,
                                               const int* __restrict__ counts,
                                               const int* __restrict__ offs,
                                               const int* __restrict__ clist) {
  int e = blockIdx.z;
  int cnt = counts[e];
  int m0 = blockIdx.x * 128;
  if (m0 >= cnt) return;
  int off = offs[e];
  int n0 = blockIdx.y * 128;
  int tid = threadIdx.x;
  int lane = tid & 63, wave = tid >> 6;
  int wm = wave >> 1, wn = wave & 1;

  __shared__ __align__(16) u16 lA[128 * 32];
  __shared__ __align__(16) u16 lB[128 * 32];

  const u16* gA[2];
  const u16* gB[2];
  int c = tid & 3;
#pragma unroll
  for (int s = 0; s < 2; s++) {
    int idx = s * 256 + tid;
    int r = idx >> 2;
    int mrow = m0 + r; if (mrow >= cnt) mrow = cnt - 1;
    gA[s] = hb + (size_t)(off + mrow) * H_DIM + c * 8;
    gB[s] = w2t + (size_t)e * E_DIM * H_DIM + (size_t)(n0 + r) * H_DIM + c * 8;
  }

  frag_cd acc[4][4] = {};
  int q = lane >> 4, mr = lane & 15;

  for (int k0 = 0; k0 < H_DIM; k0 += 32) {
#pragma unroll
    for (int s = 0; s < 2; s++) {
      gl2lds16(gA[s] + k0, lA + (size_t)(s * 256 + tid) * 8);
      gl2lds16(gB[s] + k0, lB + (size_t)(s * 256 + tid) * 8);
    }
    __syncthreads();
    frag_ab af[4], bfr[4];
#pragma unroll
    for (int i = 0; i < 4; i++)
      af[i] = *(const frag_ab*)(lA + (size_t)(wm * 64 + i * 16 + mr) * 32 + q * 8);
#pragma unroll
    for (int j = 0; j < 4; j++)
      bfr[j] = *(const frag_ab*)(lB + (size_t)(wn * 64 + j * 16 + mr) * 32 + q * 8);
#pragma unroll
    for (int i = 0; i < 4; i++)
#pragma unroll
      for (int j = 0; j < 4; j++)
        acc[i][j] = __builtin_amdgcn_mfma_f32_16x16x32_bf16(af[i], bfr[j], acc[i][j], 0, 0, 0);
    __syncthreads();
  }

  int col = lane & 15;
#pragma unroll
  for (int i = 0; i < 4; i++) {
#pragma unroll
    for (int j = 0; j < 4; j++) {
#pragma unroll
      for (int r = 0; r < 4; r++) {
        int mg = m0 + wm * 64 + i * 16 + q * 4 + r;
        if (mg < cnt) {
          int ng = n0 + wn * 64 + j * 16 + col;
          int tg = clist[off + mg];
          float v = (acc[i][j][r] + b2[e * E_DIM + ng]) * 0.5f;
          atomicAdd(out + (size_t)tg * E_DIM + ng, v);
        }
      }
    }
  }
}

extern "C" void kernel_launch(void* const* d_in, const int* in_sizes, int n_in,
                              void* d_out, int out_size, void* d_ws, size_t ws_size,
                              hipStream_t stream) {
  (void)in_sizes; (void)n_in; (void)out_size; (void)ws_size;
  const float* x  = (const float*)d_in[0];
  const float* Wr = (const float*)d_in[1];
  const float* br = (const float*)d_in[2];
  const float* W1 = (const float*)d_in[3];
  const float* b1 = (const float*)d_in[4];
  const float* W2 = (const float*)d_in[5];
  const float* b2 = (const float*)d_in[6];
  float* out = (float*)d_out;
  char* ws = (char*)d_ws;

  int* meta  = (int*)ws;                  // counts@0, cursors@+16 ints, offsets@+32 ints
  int* t2    = (int*)(ws + O_T2);
  int* clist = (int*)(ws + O_CLIST);
  u16* xb    = (u16*)(ws + O_XB);
  u16* w1t   = (u16*)(ws + O_W1T);
  u16* w2t   = (u16*)(ws + O_W2T);
  u16* hb    = (u16*)(ws + O_HB);

  // zero the accumulated output region + meta counters (ws/out re-poisoned each call)
  hipMemsetAsync(d_out, 0, (size_t)T_TOK * E_DIM * sizeof(float), stream);
  hipMemsetAsync(ws, 0, 128, stream);

  k_convx<<<dim3((T_TOK * E_DIM) / (256 * 4)), 256, 0, stream>>>(x, xb);
  k_tconv<<<dim3(H_DIM / 32, E_DIM / 32, X_EXP), 256, 0, stream>>>(W1, w1t, E_DIM, H_DIM);
  k_tconv<<<dim3(E_DIM / 32, H_DIM / 32, X_EXP), 256, 0, stream>>>(W2, w2t, H_DIM, E_DIM);
  k_router<<<dim3(T_TOK / 4), 256, 0, stream>>>(x, Wr, br, out, t2, meta);
  k_scan<<<1, 1, 0, stream>>>(meta);
  k_fill<<<dim3(T_TOK / 256), 256, 0, stream>>>(t2, meta + 16, meta + 32, clist);
  k_gemm1<<<dim3(64, H_DIM / 128, X_EXP), 256, 0, stream>>>(xb, w1t, b1, hb, meta, meta + 32, clist);
  k_gemm2<<<dim3(64, E_DIM / 128, X_EXP), 256, 0, stream>>>(hb, w2t, b2, out, meta, meta + 32, clist);
}

// Round 2
// 737.719 us; speedup vs baseline: 1.1147x; 1.1147x over previous
//
#include <hip/hip_runtime.h>
#include <hip/hip_bf16.h>
#include <math.h>

// MoE: B=8,N=1024,E=1024,H=1536,X=8,K=2. Routed (top-2 only) bf16 MFMA impl.
// R2: gemm2 atomics -> compact bf16 store + combine kernel; tanh-GELU; no out memset.
#define T_TOK 8192
#define E_DIM 1024
#define H_DIM 1536
#define X_EXP 8

typedef unsigned short u16;
typedef unsigned int u32;

typedef __attribute__((ext_vector_type(8))) short frag_ab;   // 8 bf16 (4 VGPRs)
typedef __attribute__((ext_vector_type(4))) float frag_cd;   // 4 fp32 acc

__device__ __forceinline__ u16 f2bf(float f) {
  u32 u = __float_as_uint(f);
  u32 r = u + 0x7fffu + ((u >> 16) & 1u);   // round-to-nearest-even
  return (u16)(r >> 16);
}
__device__ __forceinline__ float bf2f(u16 h) {
  return __uint_as_float(((u32)h) << 16);
}

__device__ __forceinline__ void gl2lds16(const u16* g, u16* l) {
  // async global->LDS, 16B per lane; LDS dst must be wave-uniform base + lane*16
  __builtin_amdgcn_global_load_lds((const __attribute__((address_space(1))) void*)g,
                                   (__attribute__((address_space(3))) void*)l,
                                   16, 0, 0);
}

// ---- workspace layout (bytes) ----
// meta ints: counts[8]@0, cursors[8]@64, offsets[8]@128
static const size_t O_T2    = 4096;                                   // T*2 ints
static const size_t O_CLIST = O_T2 + (size_t)T_TOK * 2 * 4;           // 69632
static const size_t O_XB    = O_CLIST + (size_t)T_TOK * 2 * 4;        // 135168
static const size_t O_W1T   = O_XB + (size_t)T_TOK * E_DIM * 2;       // 16912384
static const size_t O_W2T   = O_W1T + (size_t)X_EXP * E_DIM * H_DIM * 2; // 42078208
static const size_t O_HB    = O_W2T + (size_t)X_EXP * E_DIM * H_DIM * 2; // 67244032
// end = O_HB + 16384*1536*2 = 117575680 bytes (~112 MiB)
// y (compact gemm2 out, 16384*1024 bf16 = 33.5 MB) OVERLAYS xb+w1t (dead after gemm1).
static const size_t O_Y     = O_XB;

// ---- router: one wave per token, top-2 of logits (softmax monotonic) ----
__global__ __launch_bounds__(256) void k_router(const float* __restrict__ x,
                                                const float* __restrict__ Wr,
                                                const float* __restrict__ br,
                                                float* __restrict__ out,
                                                int* __restrict__ t2,
                                                int* __restrict__ counts) {
  int tid = threadIdx.x;
  int lane = tid & 63;
  int wave = tid >> 6;
  int t = blockIdx.x * 4 + wave;
  float acc[8];
#pragma unroll
  for (int e = 0; e < 8; e++) acc[e] = 0.f;
  const float* xr = x + (size_t)t * E_DIM;
  for (int i = lane; i < E_DIM; i += 64) {
    float xv = xr[i];
    const float* wr = Wr + (size_t)i * 8;
#pragma unroll
    for (int e = 0; e < 8; e++) acc[e] += xv * wr[e];
  }
#pragma unroll
  for (int off = 32; off; off >>= 1) {
#pragma unroll
    for (int e = 0; e < 8; e++) acc[e] += __shfl_down(acc[e], off);
  }
  if (lane == 0) {
    float lg[8];
#pragma unroll
    for (int e = 0; e < 8; e++) lg[e] = acc[e] + br[e];
    int i0 = 0; float v0 = lg[0];
#pragma unroll
    for (int e = 1; e < 8; e++) if (lg[e] > v0) { v0 = lg[e]; i0 = e; }
    int i1 = -1; float v1 = -3.4e38f;
#pragma unroll
    for (int e = 0; e < 8; e++) if (e != i0 && lg[e] > v1) { v1 = lg[e]; i1 = e; }
    // output tail: topk_idx as float (whole out buffer read as fp32 by harness)
    out[(size_t)T_TOK * E_DIM + (size_t)t * 2 + 0] = (float)i0;
    out[(size_t)T_TOK * E_DIM + (size_t)t * 2 + 1] = (float)i1;
    t2[t * 2 + 0] = i0;
    t2[t * 2 + 1] = i1;
    atomicAdd(&counts[i0], 1);
    atomicAdd(&counts[i1], 1);
  }
}

__global__ void k_scan(int* __restrict__ meta) {
  if (threadIdx.x == 0) {
    int run = 0;
    for (int e = 0; e < 8; e++) {
      meta[32 + e] = run;      // offsets
      run += meta[e];          // counts
      meta[16 + e] = 0;        // cursors
    }
  }
}

// fills clist and packs compact slot into t2: t2[t*2+k] = e | (slot<<3)
__global__ __launch_bounds__(256) void k_fill(int* __restrict__ t2,
                                              int* __restrict__ curs,
                                              const int* __restrict__ offs,
                                              int* __restrict__ clist) {
  int t = blockIdx.x * 256 + threadIdx.x;
#pragma unroll
  for (int k = 0; k < 2; k++) {
    int e = t2[t * 2 + k] & 7;
    int p = atomicAdd(&curs[e], 1);
    int slot = offs[e] + p;
    clist[slot] = t;
    t2[t * 2 + k] = e | (slot << 3);
  }
}

// ---- convert x -> bf16 ----
__global__ __launch_bounds__(256) void k_convx(const float* __restrict__ src,
                                               u16* __restrict__ dst) {
  size_t i = ((size_t)blockIdx.x * 256 + threadIdx.x) * 4;
  float4 v = *(const float4*)(src + i);
  ushort4 o;
  o.x = f2bf(v.x); o.y = f2bf(v.y); o.z = f2bf(v.z); o.w = f2bf(v.w);
  *(ushort4*)(dst + i) = o;
}

// ---- per-expert transpose+convert: src[R][C] fp32 -> dst[C][R] bf16 ----
__global__ __launch_bounds__(256) void k_tconv(const float* __restrict__ src,
                                               u16* __restrict__ dst,
                                               int R, int C) {
  __shared__ float tile[32][33];
  int e = blockIdx.z;
  const float* s = src + (size_t)e * R * C;
  u16* d = dst + (size_t)e * R * C;
  int c0 = blockIdx.x * 32, r0 = blockIdx.y * 32;
  int tc = threadIdx.x & 31, tr = threadIdx.x >> 5;  // tr in 0..7
#pragma unroll
  for (int i = 0; i < 4; i++)
    tile[tr + i * 8][tc] = s[(size_t)(r0 + tr + i * 8) * C + c0 + tc];
  __syncthreads();
#pragma unroll
  for (int i = 0; i < 4; i++)
    d[(size_t)(c0 + tr + i * 8) * R + r0 + tc] = f2bf(tile[tc][tr + i * 8]);
}

// ---- GEMM1: h = gelu(gather(x) @ W1[e] + b1[e]) -> hb (bf16, compact rows) ----
// A: xb rows via clist (M=count[e], K=E). B: W1T[e] = [H][E] (N-major). Tile 128x128.
__global__ __launch_bounds__(256) void k_gemm1(const u16* __restrict__ xb,
                                               const u16* __restrict__ w1t,
                                               const float* __restrict__ b1,
                                               u16* __restrict__ hb,
                                               const int* __restrict__ counts,
                                               const int* __restrict__ offs,
                                               const int* __restrict__ clist) {
  int e = blockIdx.z;
  int cnt = counts[e];
  int m0 = blockIdx.x * 128;
  if (m0 >= cnt) return;
  int off = offs[e];
  int n0 = blockIdx.y * 128;
  int tid = threadIdx.x;
  int lane = tid & 63, wave = tid >> 6;
  int wm = wave >> 1, wn = wave & 1;

  __shared__ __align__(16) u16 lA[128 * 32];
  __shared__ __align__(16) u16 lB[128 * 32];

  const u16* gA[2];
  const u16* gB[2];
  int c = tid & 3;
#pragma unroll
  for (int s = 0; s < 2; s++) {
    int idx = s * 256 + tid;
    int r = idx >> 2;                       // 0..127
    int mrow = m0 + r; if (mrow >= cnt) mrow = cnt - 1;  // clamp tail (masked at store)
    int tok = clist[off + mrow];
    gA[s] = xb + (size_t)tok * E_DIM + c * 8;
    gB[s] = w1t + (size_t)e * H_DIM * E_DIM + (size_t)(n0 + r) * E_DIM + c * 8;
  }

  frag_cd acc[4][4] = {};
  int q = lane >> 4, mr = lane & 15;

  for (int k0 = 0; k0 < E_DIM; k0 += 32) {
#pragma unroll
    for (int s = 0; s < 2; s++) {
      gl2lds16(gA[s] + k0, lA + (size_t)(s * 256 + tid) * 8);
      gl2lds16(gB[s] + k0, lB + (size_t)(s * 256 + tid) * 8);
    }
    __syncthreads();   // drains vmcnt (compiler-inserted) before use
    frag_ab af[4], bfr[4];
#pragma unroll
    for (int i = 0; i < 4; i++)
      af[i] = *(const frag_ab*)(lA + (size_t)(wm * 64 + i * 16 + mr) * 32 + q * 8);
#pragma unroll
    for (int j = 0; j < 4; j++)
      bfr[j] = *(const frag_ab*)(lB + (size_t)(wn * 64 + j * 16 + mr) * 32 + q * 8);
#pragma unroll
    for (int i = 0; i < 4; i++)
#pragma unroll
      for (int j = 0; j < 4; j++)
        acc[i][j] = __builtin_amdgcn_mfma_f32_16x16x32_bf16(af[i], bfr[j], acc[i][j], 0, 0, 0);
    __syncthreads();
  }

  // epilogue: D[row=q*4+r][col=lane&15] per 16x16 tile
  int col = lane & 15;
#pragma unroll
  for (int i = 0; i < 4; i++) {
#pragma unroll
    for (int j = 0; j < 4; j++) {
#pragma unroll
      for (int r = 0; r < 4; r++) {
        int mg = m0 + wm * 64 + i * 16 + q * 4 + r;
        if (mg < cnt) {
          int ng = n0 + wn * 64 + j * 16 + col;
          float v = acc[i][j][r] + b1[e * H_DIM + ng];
          // tanh-GELU via sigmoid: v * sigma(1.5957691v + 0.0713548v^3)
          float z = v * (1.5957691216f + 0.0713548162f * v * v);
          v = v / (1.0f + __expf(-z));
          hb[(size_t)(off + mg) * H_DIM + ng] = f2bf(v);
        }
      }
    }
  }
}

// ---- GEMM2: y[slot] = hb @ W2[e]  (compact bf16 store, bias/mean in combine) ----
// A: hb compact rows (K=H). B: W2T[e] = [E][H].
__global__ __launch_bounds__(256) void k_gemm2(const u16* __restrict__ hb,
                                               const u16* __restrict__ w2t,
                                               u16* __restrict__ y,
                                               const int* __restrict__ counts,
                                               const int* __restrict__ offs) {
  int e = blockIdx.z;
  int cnt = counts[e];
  int m0 = blockIdx.x * 128;
  if (m0 >= cnt) return;
  int off = offs[e];
  int n0 = blockIdx.y * 128;
  int tid = threadIdx.x;
  int lane = tid & 63, wave = tid >> 6;
  int wm = wave >> 1, wn = wave & 1;

  __shared__ __align__(16) u16 lA[128 * 32];
  __shared__ __align__(16) u16 lB[128 * 32];

  const u16* gA[2];
  const u16* gB[2];
  int c = tid & 3;
#pragma unroll
  for (int s = 0; s < 2; s++) {
    int idx = s * 256 + tid;
    int r = idx >> 2;
    int mrow = m0 + r; if (mrow >= cnt) mrow = cnt - 1;
    gA[s] = hb + (size_t)(off + mrow) * H_DIM + c * 8;
    gB[s] = w2t + (size_t)e * E_DIM * H_DIM + (size_t)(n0 + r) * H_DIM + c * 8;
  }

  frag_cd acc[4][4] = {};
  int q = lane >> 4, mr = lane & 15;

  for (int k0 = 0; k0 < H_DIM; k0 += 32) {
#pragma unroll
    for (int s = 0; s < 2; s++) {
      gl2lds16(gA[s] + k0, lA + (size_t)(s * 256 + tid) * 8);
      gl2lds16(gB[s] + k0, lB + (size_t)(s * 256 + tid) * 8);
    }
    __syncthreads();
    frag_ab af[4], bfr[4];
#pragma unroll
    for (int i = 0; i < 4; i++)
      af[i] = *(const frag_ab*)(lA + (size_t)(wm * 64 + i * 16 + mr) * 32 + q * 8);
#pragma unroll
    for (int j = 0; j < 4; j++)
      bfr[j] = *(const frag_ab*)(lB + (size_t)(wn * 64 + j * 16 + mr) * 32 + q * 8);
#pragma unroll
    for (int i = 0; i < 4; i++)
#pragma unroll
      for (int j = 0; j < 4; j++)
        acc[i][j] = __builtin_amdgcn_mfma_f32_16x16x32_bf16(af[i], bfr[j], acc[i][j], 0, 0, 0);
    __syncthreads();
  }

  int col = lane & 15;
#pragma unroll
  for (int i = 0; i < 4; i++) {
#pragma unroll
    for (int j = 0; j < 4; j++) {
#pragma unroll
      for (int r = 0; r < 4; r++) {
        int mg = m0 + wm * 64 + i * 16 + q * 4 + r;
        if (mg < cnt) {
          int ng = n0 + wn * 64 + j * 16 + col;
          y[(size_t)(off + mg) * E_DIM + ng] = f2bf(acc[i][j][r]);
        }
      }
    }
  }
}

// ---- combine: out[t] = 0.5*(y[slot0] + y[slot1] + b2[e0] + b2[e1]) ----
__global__ __launch_bounds__(256) void k_combine(const u16* __restrict__ y,
                                                 const float* __restrict__ b2,
                                                 const int* __restrict__ t2,
                                                 float* __restrict__ out) {
  int t = blockIdx.x;
  int c = threadIdx.x * 4;
  int v0 = t2[t * 2 + 0], v1 = t2[t * 2 + 1];
  int e0 = v0 & 7, s0 = v0 >> 3;
  int e1 = v1 & 7, s1 = v1 >> 3;
  ushort4 a = *(const ushort4*)(y + (size_t)s0 * E_DIM + c);
  ushort4 b = *(const ushort4*)(y + (size_t)s1 * E_DIM + c);
  float4 p0 = *(const float4*)(b2 + (size_t)e0 * E_DIM + c);
  float4 p1 = *(const float4*)(b2 + (size_t)e1 * E_DIM + c);
  float4 o;
  o.x = 0.5f * (bf2f(a.x) + bf2f(b.x) + p0.x + p1.x);
  o.y = 0.5f * (bf2f(a.y) + bf2f(b.y) + p0.y + p1.y);
  o.z = 0.5f * (bf2f(a.z) + bf2f(b.z) + p0.z + p1.z);
  o.w = 0.5f * (bf2f(a.w) + bf2f(b.w) + p0.w + p1.w);
  *(float4*)(out + (size_t)t * E_DIM + c) = o;
}

extern "C" void kernel_launch(void* const* d_in, const int* in_sizes, int n_in,
                              void* d_out, int out_size, void* d_ws, size_t ws_size,
                              hipStream_t stream) {
  (void)in_sizes; (void)n_in; (void)out_size; (void)ws_size;
  const float* x  = (const float*)d_in[0];
  const float* Wr = (const float*)d_in[1];
  const float* br = (const float*)d_in[2];
  const float* W1 = (const float*)d_in[3];
  const float* b1 = (const float*)d_in[4];
  const float* W2 = (const float*)d_in[5];
  const float* b2 = (const float*)d_in[6];
  float* out = (float*)d_out;
  char* ws = (char*)d_ws;

  int* meta  = (int*)ws;                  // counts@0, cursors@+16 ints, offsets@+32 ints
  int* t2    = (int*)(ws + O_T2);
  int* clist = (int*)(ws + O_CLIST);
  u16* xb    = (u16*)(ws + O_XB);
  u16* w1t   = (u16*)(ws + O_W1T);
  u16* w2t   = (u16*)(ws + O_W2T);
  u16* hb    = (u16*)(ws + O_HB);
  u16* y     = (u16*)(ws + O_Y);          // overlays xb+w1t (dead after gemm1)

  hipMemsetAsync(ws, 0, 128, stream);     // zero counts (+cursors; offsets set by k_scan)

  k_convx<<<dim3((T_TOK * E_DIM) / (256 * 4)), 256, 0, stream>>>(x, xb);
  k_tconv<<<dim3(H_DIM / 32, E_DIM / 32, X_EXP), 256, 0, stream>>>(W1, w1t, E_DIM, H_DIM);
  k_tconv<<<dim3(E_DIM / 32, H_DIM / 32, X_EXP), 256, 0, stream>>>(W2, w2t, H_DIM, E_DIM);
  k_router<<<dim3(T_TOK / 4), 256, 0, stream>>>(x, Wr, br, out, t2, meta);
  k_scan<<<1, 1, 0, stream>>>(meta);
  k_fill<<<dim3(T_TOK / 256), 256, 0, stream>>>(t2, meta + 16, meta + 32, clist);
  k_gemm1<<<dim3(64, H_DIM / 128, X_EXP), 256, 0, stream>>>(xb, w1t, b1, hb, meta, meta + 32, clist);
  k_gemm2<<<dim3(64, E_DIM / 128, X_EXP), 256, 0, stream>>>(hb, w2t, y, meta, meta + 32);
  k_combine<<<dim3(T_TOK), 256, 0, stream>>>(y, b2, t2, out);
}

// Round 4
// 713.507 us; speedup vs baseline: 1.1525x; 1.0339x over previous
//
#include <hip/hip_runtime.h>
#include <hip/hip_bf16.h>
#include <math.h>

// MoE: B=8,N=1024,E=1024,H=1536,X=8,K=2. Routed (top-2 only) bf16 MFMA impl.
// R4: fix k_prep convx OOB (4 iters not 16); otherwise identical to R3.
#define T_TOK 8192
#define E_DIM 1024
#define H_DIM 1536
#define X_EXP 8

typedef unsigned short u16;
typedef unsigned int u32;

typedef __attribute__((ext_vector_type(8))) short frag_ab;   // 8 bf16 (4 VGPRs)
typedef __attribute__((ext_vector_type(4))) float frag_cd;   // 4 fp32 acc

__device__ __forceinline__ u16 f2bf(float f) {
  u32 u = __float_as_uint(f);
  u32 r = u + 0x7fffu + ((u >> 16) & 1u);   // round-to-nearest-even
  return (u16)(r >> 16);
}
__device__ __forceinline__ float bf2f(u16 h) {
  return __uint_as_float(((u32)h) << 16);
}

__device__ __forceinline__ void gl2lds16(const u16* g, u16* l) {
  // async global->LDS, 16B per lane; LDS dst must be wave-uniform base + lane*16
  __builtin_amdgcn_global_load_lds((const __attribute__((address_space(1))) void*)g,
                                   (__attribute__((address_space(3))) void*)l,
                                   16, 0, 0);
}

// ---- workspace layout (bytes) ----
// meta ints: counts[8]@0, cursors[8]@64
static const size_t O_T2    = 4096;                                   // T*2 ints
static const size_t O_CLIST = O_T2 + (size_t)T_TOK * 2 * 4;           // 69632
static const size_t O_XB    = O_CLIST + (size_t)T_TOK * 2 * 4;        // 135168
static const size_t O_W1T   = O_XB + (size_t)T_TOK * E_DIM * 2;       // 16912384
static const size_t O_W2T   = O_W1T + (size_t)X_EXP * E_DIM * H_DIM * 2; // 42078208
static const size_t O_HB    = O_W2T + (size_t)X_EXP * E_DIM * H_DIM * 2; // 67244032
// end = O_HB + 16384*1536*2 = 117575680 bytes (~112 MiB)
// y (compact gemm2 out, 16384*1024 bf16 = 33.5 MB) OVERLAYS xb+w1t (dead after gemm1).
static const size_t O_Y     = O_XB;

// ---- fused prep: convx | router | tconv W1 | tconv W2, by block range ----
// blocks [0,2048): convx — 4096 elems/block (4 iters x 1024)
// blocks [2048,4096): router — 4 tokens/block, Wr transposed in LDS
// blocks [4096,16384): tconv W1 [E][H]->[H][E] per expert
// blocks [16384,28672): tconv W2 [H][E]->[E][H] per expert
__global__ __launch_bounds__(256) void k_prep(const float* __restrict__ x,
                                              const float* __restrict__ Wr,
                                              const float* __restrict__ br,
                                              const float* __restrict__ W1,
                                              const float* __restrict__ W2,
                                              float* __restrict__ out,
                                              u16* __restrict__ xb,
                                              u16* __restrict__ w1t,
                                              u16* __restrict__ w2t,
                                              int* __restrict__ t2,
                                              int* __restrict__ counts) {
  __shared__ union {
    float wrT[8 * 1024];      // 32 KB
    float tile[32][33];
  } sm;
  int blk = blockIdx.x;
  int tid = threadIdx.x;

  if (blk < 2048) {
    // ---- convx: x fp32 -> xb bf16; T*E = 8388608 = 2048 blocks * 4096 ----
    size_t base = (size_t)blk * 4096 + tid * 4;
#pragma unroll
    for (int it = 0; it < 4; it++) {
      size_t i = base + (size_t)it * 1024;
      float4 v = *(const float4*)(x + i);
      ushort4 o;
      o.x = f2bf(v.x); o.y = f2bf(v.y); o.z = f2bf(v.z); o.w = f2bf(v.w);
      *(ushort4*)(xb + i) = o;
    }
  } else if (blk < 4096) {
    // ---- router: logits via LDS-transposed Wr, top-2 ----
    for (int g = tid; g < 8192; g += 256)
      sm.wrT[(g & 7) * 1024 + (g >> 3)] = Wr[g];
    __syncthreads();
    int lane = tid & 63, wave = tid >> 6;
    int t = (blk - 2048) * 4 + wave;
    const float* xr = x + (size_t)t * E_DIM;
    float acc[8];
#pragma unroll
    for (int e = 0; e < 8; e++) acc[e] = 0.f;
#pragma unroll 4
    for (int k = 0; k < 16; k++) {
      int i = lane + k * 64;
      float xv = xr[i];
#pragma unroll
      for (int e = 0; e < 8; e++) acc[e] += xv * sm.wrT[e * 1024 + i];
    }
#pragma unroll
    for (int off = 32; off; off >>= 1) {
#pragma unroll
      for (int e = 0; e < 8; e++) acc[e] += __shfl_down(acc[e], off);
    }
    if (lane == 0) {
      float lg[8];
#pragma unroll
      for (int e = 0; e < 8; e++) lg[e] = acc[e] + br[e];
      int i0 = 0; float v0 = lg[0];
#pragma unroll
      for (int e = 1; e < 8; e++) if (lg[e] > v0) { v0 = lg[e]; i0 = e; }
      int i1 = -1; float v1 = -3.4e38f;
#pragma unroll
      for (int e = 0; e < 8; e++) if (e != i0 && lg[e] > v1) { v1 = lg[e]; i1 = e; }
      out[(size_t)T_TOK * E_DIM + (size_t)t * 2 + 0] = (float)i0;
      out[(size_t)T_TOK * E_DIM + (size_t)t * 2 + 1] = (float)i1;
      t2[t * 2 + 0] = i0;
      t2[t * 2 + 1] = i1;
      atomicAdd(&counts[i0], 1);
      atomicAdd(&counts[i1], 1);
    }
  } else {
    // ---- tconv: src[R][C] fp32 -> dst[C][R] bf16, per expert ----
    const float* src; u16* dst; int R, C, bx, by, e;
    if (blk < 16384) {
      int l = blk - 4096;           // W1: R=E=1024, C=H=1536, grid (48,32,8)
      bx = l % 48; by = (l / 48) % 32; e = l / (48 * 32);
      R = E_DIM; C = H_DIM;
      src = W1 + (size_t)e * R * C; dst = w1t + (size_t)e * R * C;
    } else {
      int l = blk - 16384;          // W2: R=H=1536, C=E=1024, grid (32,48,8)
      bx = l % 32; by = (l / 32) % 48; e = l / (32 * 48);
      R = H_DIM; C = E_DIM;
      src = W2 + (size_t)e * R * C; dst = w2t + (size_t)e * R * C;
    }
    int c0 = bx * 32, r0 = by * 32;
    int tc = tid & 31, tr = tid >> 5;  // tr in 0..7
#pragma unroll
    for (int i = 0; i < 4; i++)
      sm.tile[tr + i * 8][tc] = src[(size_t)(r0 + tr + i * 8) * C + c0 + tc];
    __syncthreads();
#pragma unroll
    for (int i = 0; i < 4; i++)
      dst[(size_t)(c0 + tr + i * 8) * R + r0 + tc] = f2bf(sm.tile[tc][tr + i * 8]);
  }
}

// fills clist and packs compact slot into t2: t2[t*2+k] = e | (slot<<3)
// offsets computed locally as exclusive prefix of counts.
__global__ __launch_bounds__(256) void k_fill(int* __restrict__ t2,
                                              const int* __restrict__ counts,
                                              int* __restrict__ curs,
                                              int* __restrict__ clist) {
  int offs[8];
  {
    int run = 0;
#pragma unroll
    for (int e = 0; e < 8; e++) { offs[e] = run; run += counts[e]; }
  }
  int t = blockIdx.x * 256 + threadIdx.x;
#pragma unroll
  for (int k = 0; k < 2; k++) {
    int e = t2[t * 2 + k] & 7;
    int p = atomicAdd(&curs[e], 1);
    int slot = offs[e] + p;
    clist[slot] = t;
    t2[t * 2 + k] = e | (slot << 3);
  }
}

// ---- GEMM1: h = gelu(gather(x) @ W1[e] + b1[e]) -> hb (bf16, compact rows) ----
__global__ __launch_bounds__(256) void k_gemm1(const u16* __restrict__ xb,
                                               const u16* __restrict__ w1t,
                                               const float* __restrict__ b1,
                                               u16* __restrict__ hb,
                                               const int* __restrict__ counts,
                                               const int* __restrict__ clist) {
  int e = blockIdx.z;
  int cnt = counts[e];
  int m0 = blockIdx.x * 128;
  if (m0 >= cnt) return;
  int off = 0;
  for (int j = 0; j < 8; j++) off += (j < e) ? counts[j] : 0;
  int n0 = blockIdx.y * 128;
  int tid = threadIdx.x;
  int lane = tid & 63, wave = tid >> 6;
  int wm = wave >> 1, wn = wave & 1;

  __shared__ __align__(16) u16 lA[128 * 32];
  __shared__ __align__(16) u16 lB[128 * 32];

  const u16* gA[2];
  const u16* gB[2];
  int c = tid & 3;
#pragma unroll
  for (int s = 0; s < 2; s++) {
    int idx = s * 256 + tid;
    int r = idx >> 2;                       // 0..127
    int mrow = m0 + r; if (mrow >= cnt) mrow = cnt - 1;  // clamp tail (masked at store)
    int tok = clist[off + mrow];
    gA[s] = xb + (size_t)tok * E_DIM + c * 8;
    gB[s] = w1t + (size_t)e * H_DIM * E_DIM + (size_t)(n0 + r) * E_DIM + c * 8;
  }

  frag_cd acc[4][4] = {};
  int q = lane >> 4, mr = lane & 15;

  for (int k0 = 0; k0 < E_DIM; k0 += 32) {
#pragma unroll
    for (int s = 0; s < 2; s++) {
      gl2lds16(gA[s] + k0, lA + (size_t)(s * 256 + tid) * 8);
      gl2lds16(gB[s] + k0, lB + (size_t)(s * 256 + tid) * 8);
    }
    __syncthreads();
    frag_ab af[4], bfr[4];
#pragma unroll
    for (int i = 0; i < 4; i++)
      af[i] = *(const frag_ab*)(lA + (size_t)(wm * 64 + i * 16 + mr) * 32 + q * 8);
#pragma unroll
    for (int j = 0; j < 4; j++)
      bfr[j] = *(const frag_ab*)(lB + (size_t)(wn * 64 + j * 16 + mr) * 32 + q * 8);
#pragma unroll
    for (int i = 0; i < 4; i++)
#pragma unroll
      for (int j = 0; j < 4; j++)
        acc[i][j] = __builtin_amdgcn_mfma_f32_16x16x32_bf16(af[i], bfr[j], acc[i][j], 0, 0, 0);
    __syncthreads();
  }

  int col = lane & 15;
#pragma unroll
  for (int i = 0; i < 4; i++) {
#pragma unroll
    for (int j = 0; j < 4; j++) {
#pragma unroll
      for (int r = 0; r < 4; r++) {
        int mg = m0 + wm * 64 + i * 16 + q * 4 + r;
        if (mg < cnt) {
          int ng = n0 + wn * 64 + j * 16 + col;
          float v = acc[i][j][r] + b1[e * H_DIM + ng];
          // tanh-GELU via sigmoid: v * sigma(1.5957691v + 0.0713548v^3)
          float z = v * (1.5957691216f + 0.0713548162f * v * v);
          v = v / (1.0f + __expf(-z));
          hb[(size_t)(off + mg) * H_DIM + ng] = f2bf(v);
        }
      }
    }
  }
}

// ---- GEMM2: y[slot] = hb @ W2[e]  (compact bf16 store, bias/mean in combine) ----
__global__ __launch_bounds__(256) void k_gemm2(const u16* __restrict__ hb,
                                               const u16* __restrict__ w2t,
                                               u16* __restrict__ y,
                                               const int* __restrict__ counts) {
  int e = blockIdx.z;
  int cnt = counts[e];
  int m0 = blockIdx.x * 128;
  if (m0 >= cnt) return;
  int off = 0;
  for (int j = 0; j < 8; j++) off += (j < e) ? counts[j] : 0;
  int n0 = blockIdx.y * 128;
  int tid = threadIdx.x;
  int lane = tid & 63, wave = tid >> 6;
  int wm = wave >> 1, wn = wave & 1;

  __shared__ __align__(16) u16 lA[128 * 32];
  __shared__ __align__(16) u16 lB[128 * 32];

  const u16* gA[2];
  const u16* gB[2];
  int c = tid & 3;
#pragma unroll
  for (int s = 0; s < 2; s++) {
    int idx = s * 256 + tid;
    int r = idx >> 2;
    int mrow = m0 + r; if (mrow >= cnt) mrow = cnt - 1;
    gA[s] = hb + (size_t)(off + mrow) * H_DIM + c * 8;
    gB[s] = w2t + (size_t)e * E_DIM * H_DIM + (size_t)(n0 + r) * H_DIM + c * 8;
  }

  frag_cd acc[4][4] = {};
  int q = lane >> 4, mr = lane & 15;

  for (int k0 = 0; k0 < H_DIM; k0 += 32) {
#pragma unroll
    for (int s = 0; s < 2; s++) {
      gl2lds16(gA[s] + k0, lA + (size_t)(s * 256 + tid) * 8);
      gl2lds16(gB[s] + k0, lB + (size_t)(s * 256 + tid) * 8);
    }
    __syncthreads();
    frag_ab af[4], bfr[4];
#pragma unroll
    for (int i = 0; i < 4; i++)
      af[i] = *(const frag_ab*)(lA + (size_t)(wm * 64 + i * 16 + mr) * 32 + q * 8);
#pragma unroll
    for (int j = 0; j < 4; j++)
      bfr[j] = *(const frag_ab*)(lB + (size_t)(wn * 64 + j * 16 + mr) * 32 + q * 8);
#pragma unroll
    for (int i = 0; i < 4; i++)
#pragma unroll
      for (int j = 0; j < 4; j++)
        acc[i][j] = __builtin_amdgcn_mfma_f32_16x16x32_bf16(af[i], bfr[j], acc[i][j], 0, 0, 0);
    __syncthreads();
  }

  int col = lane & 15;
#pragma unroll
  for (int i = 0; i < 4; i++) {
#pragma unroll
    for (int j = 0; j < 4; j++) {
#pragma unroll
      for (int r = 0; r < 4; r++) {
        int mg = m0 + wm * 64 + i * 16 + q * 4 + r;
        if (mg < cnt) {
          int ng = n0 + wn * 64 + j * 16 + col;
          y[(size_t)(off + mg) * E_DIM + ng] = f2bf(acc[i][j][r]);
        }
      }
    }
  }
}

// ---- combine: out[t] = 0.5*(y[slot0] + y[slot1] + b2[e0] + b2[e1]) ----
__global__ __launch_bounds__(256) void k_combine(const u16* __restrict__ y,
                                                 const float* __restrict__ b2,
                                                 const int* __restrict__ t2,
                                                 float* __restrict__ out) {
  int t = blockIdx.x;
  int c = threadIdx.x * 4;
  int v0 = t2[t * 2 + 0], v1 = t2[t * 2 + 1];
  int e0 = v0 & 7, s0 = v0 >> 3;
  int e1 = v1 & 7, s1 = v1 >> 3;
  ushort4 a = *(const ushort4*)(y + (size_t)s0 * E_DIM + c);
  ushort4 b = *(const ushort4*)(y + (size_t)s1 * E_DIM + c);
  float4 p0 = *(const float4*)(b2 + (size_t)e0 * E_DIM + c);
  float4 p1 = *(const float4*)(b2 + (size_t)e1 * E_DIM + c);
  float4 o;
  o.x = 0.5f * (bf2f(a.x) + bf2f(b.x) + p0.x + p1.x);
  o.y = 0.5f * (bf2f(a.y) + bf2f(b.y) + p0.y + p1.y);
  o.z = 0.5f * (bf2f(a.z) + bf2f(b.z) + p0.z + p1.z);
  o.w = 0.5f * (bf2f(a.w) + bf2f(b.w) + p0.w + p1.w);
  *(float4*)(out + (size_t)t * E_DIM + c) = o;
}

extern "C" void kernel_launch(void* const* d_in, const int* in_sizes, int n_in,
                              void* d_out, int out_size, void* d_ws, size_t ws_size,
                              hipStream_t stream) {
  (void)in_sizes; (void)n_in; (void)out_size; (void)ws_size;
  const float* x  = (const float*)d_in[0];
  const float* Wr = (const float*)d_in[1];
  const float* br = (const float*)d_in[2];
  const float* W1 = (const float*)d_in[3];
  const float* b1 = (const float*)d_in[4];
  const float* W2 = (const float*)d_in[5];
  const float* b2 = (const float*)d_in[6];
  float* out = (float*)d_out;
  char* ws = (char*)d_ws;

  int* meta  = (int*)ws;                  // counts@0, cursors@+16 ints
  int* t2    = (int*)(ws + O_T2);
  int* clist = (int*)(ws + O_CLIST);
  u16* xb    = (u16*)(ws + O_XB);
  u16* w1t   = (u16*)(ws + O_W1T);
  u16* w2t   = (u16*)(ws + O_W2T);
  u16* hb    = (u16*)(ws + O_HB);
  u16* y     = (u16*)(ws + O_Y);          // overlays xb+w1t (dead after gemm1)

  hipMemsetAsync(ws, 0, 128, stream);     // zero counts + cursors

  k_prep<<<dim3(28672), 256, 0, stream>>>(x, Wr, br, W1, W2, out, xb, w1t, w2t, t2, meta);
  k_fill<<<dim3(T_TOK / 256), 256, 0, stream>>>(t2, meta, meta + 16, clist);
  k_gemm1<<<dim3(64, H_DIM / 128, X_EXP), 256, 0, stream>>>(xb, w1t, b1, hb, meta, clist);
  k_gemm2<<<dim3(64, E_DIM / 128, X_EXP), 256, 0, stream>>>(hb, w2t, y, meta);
  k_combine<<<dim3(T_TOK), 256, 0, stream>>>(y, b2, t2, out);
}

// Round 5
// 577.136 us; speedup vs baseline: 1.4248x; 1.2363x over previous
//
#include <hip/hip_runtime.h>
#include <hip/hip_bf16.h>
#include <math.h>

// MoE: B=8,N=1024,E=1024,H=1536,X=8,K=2. Routed (top-2 only) bf16 MFMA impl.
// R5: router fused into convx (register-resident Wr, reuses conv loads);
//     tconv 64x64 tiles (6144 blocks, float4 loads, [64][65] LDS).
#define T_TOK 8192
#define E_DIM 1024
#define H_DIM 1536
#define X_EXP 8

typedef unsigned short u16;
typedef unsigned int u32;

typedef __attribute__((ext_vector_type(8))) short frag_ab;   // 8 bf16 (4 VGPRs)
typedef __attribute__((ext_vector_type(4))) float frag_cd;   // 4 fp32 acc

__device__ __forceinline__ u16 f2bf(float f) {
  u32 u = __float_as_uint(f);
  u32 r = u + 0x7fffu + ((u >> 16) & 1u);   // round-to-nearest-even
  return (u16)(r >> 16);
}
__device__ __forceinline__ float bf2f(u16 h) {
  return __uint_as_float(((u32)h) << 16);
}

__device__ __forceinline__ void gl2lds16(const u16* g, u16* l) {
  // async global->LDS, 16B per lane; LDS dst must be wave-uniform base + lane*16
  __builtin_amdgcn_global_load_lds((const __attribute__((address_space(1))) void*)g,
                                   (__attribute__((address_space(3))) void*)l,
                                   16, 0, 0);
}

// ---- workspace layout (bytes) ----
// meta ints: counts[8]@0, cursors[8]@64
static const size_t O_T2    = 4096;                                   // T*2 ints
static const size_t O_CLIST = O_T2 + (size_t)T_TOK * 2 * 4;           // 69632
static const size_t O_XB    = O_CLIST + (size_t)T_TOK * 2 * 4;        // 135168
static const size_t O_W1T   = O_XB + (size_t)T_TOK * E_DIM * 2;       // 16912384
static const size_t O_W2T   = O_W1T + (size_t)X_EXP * E_DIM * H_DIM * 2; // 42078208
static const size_t O_HB    = O_W2T + (size_t)X_EXP * E_DIM * H_DIM * 2; // 67244032
// end = O_HB + 16384*1536*2 = 117575680 bytes (~112 MiB)
// y (compact gemm2 out, 16384*1024 bf16 = 33.5 MB) OVERLAYS xb+w1t (dead after gemm1).
static const size_t O_Y     = O_XB;

// ---- fused prep ----
// blocks [0,2048): convx + router — 4 tokens/block; Wr in registers; logits
//                  accumulated from the same float4 loads used for conversion.
// blocks [2048,5120): tconv W1 [E][H]->[H][E], 64x64 tiles, grid (24,16,8)
// blocks [5120,8192): tconv W2 [H][E]->[E][H], 64x64 tiles, grid (16,24,8)
__global__ __launch_bounds__(256) void k_prep(const float* __restrict__ x,
                                              const float* __restrict__ Wr,
                                              const float* __restrict__ br,
                                              const float* __restrict__ W1,
                                              const float* __restrict__ W2,
                                              float* __restrict__ out,
                                              u16* __restrict__ xb,
                                              u16* __restrict__ w1t,
                                              u16* __restrict__ w2t,
                                              int* __restrict__ t2,
                                              int* __restrict__ counts) {
  __shared__ union {
    float tile[64][65];       // 16.6 KB, odd stride -> conflict-free transpose reads
    float red[4][4][8];       // wave x token-it x expert partials
  } sm;
  int blk = blockIdx.x;
  int tid = threadIdx.x;

  if (blk < 2048) {
    // ---- convx + router: tokens 4*blk .. 4*blk+3 ----
    // Thread covers positions p = tid*4..tid*4+3 of each token.
    // Register-resident Wr[p][e]: 32 floats = 8 float4, coalesced load.
    float4 wq[8];
    {
      const float4* wr4 = (const float4*)Wr + (size_t)tid * 8;
#pragma unroll
      for (int j = 0; j < 8; j++) wq[j] = wr4[j];
    }
    float acc[4][8];
#pragma unroll
    for (int it = 0; it < 4; it++)
#pragma unroll
      for (int e = 0; e < 8; e++) acc[it][e] = 0.f;

#pragma unroll
    for (int it = 0; it < 4; it++) {
      size_t base = (size_t)blk * 4096 + it * 1024 + tid * 4;
      float4 v = *(const float4*)(x + base);
      ushort4 o;
      o.x = f2bf(v.x); o.y = f2bf(v.y); o.z = f2bf(v.z); o.w = f2bf(v.w);
      *(ushort4*)(xb + base) = o;
      float xv[4] = {v.x, v.y, v.z, v.w};
#pragma unroll
      for (int j = 0; j < 4; j++) {
        // Wr[p=tid*4+j][e] = wq[j*2 + (e>>2)] component (e&3)
#pragma unroll
        for (int e = 0; e < 8; e++) {
          float4 q = wq[j * 2 + (e >> 2)];
          float wv = (e & 3) == 0 ? q.x : (e & 3) == 1 ? q.y : (e & 3) == 2 ? q.z : q.w;
          acc[it][e] += xv[j] * wv;
        }
      }
    }
    // wave shuffle reduction (64 lanes)
#pragma unroll
    for (int off = 32; off; off >>= 1)
#pragma unroll
      for (int it = 0; it < 4; it++)
#pragma unroll
        for (int e = 0; e < 8; e++)
          acc[it][e] += __shfl_down(acc[it][e], off);
    int lane = tid & 63, wave = tid >> 6;
    if (lane == 0) {
#pragma unroll
      for (int it = 0; it < 4; it++)
#pragma unroll
        for (int e = 0; e < 8; e++) sm.red[wave][it][e] = acc[it][e];
    }
    __syncthreads();
    if (tid < 4) {
      int t = blk * 4 + tid;
      float lg[8];
#pragma unroll
      for (int e = 0; e < 8; e++)
        lg[e] = sm.red[0][tid][e] + sm.red[1][tid][e] + sm.red[2][tid][e] + sm.red[3][tid][e] + br[e];
      int i0 = 0; float v0 = lg[0];
#pragma unroll
      for (int e = 1; e < 8; e++) if (lg[e] > v0) { v0 = lg[e]; i0 = e; }
      int i1 = -1; float v1 = -3.4e38f;
#pragma unroll
      for (int e = 0; e < 8; e++) if (e != i0 && lg[e] > v1) { v1 = lg[e]; i1 = e; }
      out[(size_t)T_TOK * E_DIM + (size_t)t * 2 + 0] = (float)i0;
      out[(size_t)T_TOK * E_DIM + (size_t)t * 2 + 1] = (float)i1;
      t2[t * 2 + 0] = i0;
      t2[t * 2 + 1] = i1;
      atomicAdd(&counts[i0], 1);
      atomicAdd(&counts[i1], 1);
    }
  } else {
    // ---- tconv 64x64: src[R][C] fp32 -> dst[C][R] bf16, per expert ----
    const float* src; u16* dst; int R, C, bx, by, e;
    if (blk < 5120) {
      int l = blk - 2048;           // W1: R=E=1024, C=H=1536, grid (24,16,8)
      bx = l % 24; by = (l / 24) % 16; e = l / 384;
      R = E_DIM; C = H_DIM;
      src = W1 + (size_t)e * R * C; dst = w1t + (size_t)e * R * C;
    } else {
      int l = blk - 5120;           // W2: R=H=1536, C=E=1024, grid (16,24,8)
      bx = l % 16; by = (l / 16) % 24; e = l / 384;
      R = H_DIM; C = E_DIM;
      src = W2 + (size_t)e * R * C; dst = w2t + (size_t)e * R * C;
    }
    int c0 = bx * 64, r0 = by * 64;
    int tc = tid & 15, tr = tid >> 4;   // tc: 16 x float4 = 64 cols; tr: 16 rows
#pragma unroll
    for (int i = 0; i < 4; i++) {
      int rr = tr + i * 16;
      float4 v = *(const float4*)(src + (size_t)(r0 + rr) * C + c0 + tc * 4);
      sm.tile[rr][tc * 4 + 0] = v.x;
      sm.tile[rr][tc * 4 + 1] = v.y;
      sm.tile[rr][tc * 4 + 2] = v.z;
      sm.tile[rr][tc * 4 + 3] = v.w;
    }
    __syncthreads();
#pragma unroll
    for (int i = 0; i < 4; i++) {
      int hh = tr + i * 16;             // output row within tile (src col)
      ushort4 o;
      o.x = f2bf(sm.tile[tc * 4 + 0][hh]);
      o.y = f2bf(sm.tile[tc * 4 + 1][hh]);
      o.z = f2bf(sm.tile[tc * 4 + 2][hh]);
      o.w = f2bf(sm.tile[tc * 4 + 3][hh]);
      *(ushort4*)(dst + (size_t)(c0 + hh) * R + r0 + tc * 4) = o;
    }
  }
}

// fills clist and packs compact slot into t2: t2[t*2+k] = e | (slot<<3)
// offsets computed locally as exclusive prefix of counts.
__global__ __launch_bounds__(256) void k_fill(int* __restrict__ t2,
                                              const int* __restrict__ counts,
                                              int* __restrict__ curs,
                                              int* __restrict__ clist) {
  int offs[8];
  {
    int run = 0;
#pragma unroll
    for (int e = 0; e < 8; e++) { offs[e] = run; run += counts[e]; }
  }
  int t = blockIdx.x * 256 + threadIdx.x;
#pragma unroll
  for (int k = 0; k < 2; k++) {
    int e = t2[t * 2 + k] & 7;
    int p = atomicAdd(&curs[e], 1);
    int slot = offs[e] + p;
    clist[slot] = t;
    t2[t * 2 + k] = e | (slot << 3);
  }
}

// ---- GEMM1: h = gelu(gather(x) @ W1[e] + b1[e]) -> hb (bf16, compact rows) ----
__global__ __launch_bounds__(256) void k_gemm1(const u16* __restrict__ xb,
                                               const u16* __restrict__ w1t,
                                               const float* __restrict__ b1,
                                               u16* __restrict__ hb,
                                               const int* __restrict__ counts,
                                               const int* __restrict__ clist) {
  int e = blockIdx.z;
  int cnt = counts[e];
  int m0 = blockIdx.x * 128;
  if (m0 >= cnt) return;
  int off = 0;
  for (int j = 0; j < 8; j++) off += (j < e) ? counts[j] : 0;
  int n0 = blockIdx.y * 128;
  int tid = threadIdx.x;
  int lane = tid & 63, wave = tid >> 6;
  int wm = wave >> 1, wn = wave & 1;

  __shared__ __align__(16) u16 lA[128 * 32];
  __shared__ __align__(16) u16 lB[128 * 32];

  const u16* gA[2];
  const u16* gB[2];
  int c = tid & 3;
#pragma unroll
  for (int s = 0; s < 2; s++) {
    int idx = s * 256 + tid;
    int r = idx >> 2;                       // 0..127
    int mrow = m0 + r; if (mrow >= cnt) mrow = cnt - 1;  // clamp tail (masked at store)
    int tok = clist[off + mrow];
    gA[s] = xb + (size_t)tok * E_DIM + c * 8;
    gB[s] = w1t + (size_t)e * H_DIM * E_DIM + (size_t)(n0 + r) * E_DIM + c * 8;
  }

  frag_cd acc[4][4] = {};
  int q = lane >> 4, mr = lane & 15;

  for (int k0 = 0; k0 < E_DIM; k0 += 32) {
#pragma unroll
    for (int s = 0; s < 2; s++) {
      gl2lds16(gA[s] + k0, lA + (size_t)(s * 256 + tid) * 8);
      gl2lds16(gB[s] + k0, lB + (size_t)(s * 256 + tid) * 8);
    }
    __syncthreads();
    frag_ab af[4], bfr[4];
#pragma unroll
    for (int i = 0; i < 4; i++)
      af[i] = *(const frag_ab*)(lA + (size_t)(wm * 64 + i * 16 + mr) * 32 + q * 8);
#pragma unroll
    for (int j = 0; j < 4; j++)
      bfr[j] = *(const frag_ab*)(lB + (size_t)(wn * 64 + j * 16 + mr) * 32 + q * 8);
#pragma unroll
    for (int i = 0; i < 4; i++)
#pragma unroll
      for (int j = 0; j < 4; j++)
        acc[i][j] = __builtin_amdgcn_mfma_f32_16x16x32_bf16(af[i], bfr[j], acc[i][j], 0, 0, 0);
    __syncthreads();
  }

  int col = lane & 15;
#pragma unroll
  for (int i = 0; i < 4; i++) {
#pragma unroll
    for (int j = 0; j < 4; j++) {
#pragma unroll
      for (int r = 0; r < 4; r++) {
        int mg = m0 + wm * 64 + i * 16 + q * 4 + r;
        if (mg < cnt) {
          int ng = n0 + wn * 64 + j * 16 + col;
          float v = acc[i][j][r] + b1[e * H_DIM + ng];
          // tanh-GELU via sigmoid: v * sigma(1.5957691v + 0.0713548v^3)
          float z = v * (1.5957691216f + 0.0713548162f * v * v);
          v = v / (1.0f + __expf(-z));
          hb[(size_t)(off + mg) * H_DIM + ng] = f2bf(v);
        }
      }
    }
  }
}

// ---- GEMM2: y[slot] = hb @ W2[e]  (compact bf16 store, bias/mean in combine) ----
__global__ __launch_bounds__(256) void k_gemm2(const u16* __restrict__ hb,
                                               const u16* __restrict__ w2t,
                                               u16* __restrict__ y,
                                               const int* __restrict__ counts) {
  int e = blockIdx.z;
  int cnt = counts[e];
  int m0 = blockIdx.x * 128;
  if (m0 >= cnt) return;
  int off = 0;
  for (int j = 0; j < 8; j++) off += (j < e) ? counts[j] : 0;
  int n0 = blockIdx.y * 128;
  int tid = threadIdx.x;
  int lane = tid & 63, wave = tid >> 6;
  int wm = wave >> 1, wn = wave & 1;

  __shared__ __align__(16) u16 lA[128 * 32];
  __shared__ __align__(16) u16 lB[128 * 32];

  const u16* gA[2];
  const u16* gB[2];
  int c = tid & 3;
#pragma unroll
  for (int s = 0; s < 2; s++) {
    int idx = s * 256 + tid;
    int r = idx >> 2;
    int mrow = m0 + r; if (mrow >= cnt) mrow = cnt - 1;
    gA[s] = hb + (size_t)(off + mrow) * H_DIM + c * 8;
    gB[s] = w2t + (size_t)e * E_DIM * H_DIM + (size_t)(n0 + r) * H_DIM + c * 8;
  }

  frag_cd acc[4][4] = {};
  int q = lane >> 4, mr = lane & 15;

  for (int k0 = 0; k0 < H_DIM; k0 += 32) {
#pragma unroll
    for (int s = 0; s < 2; s++) {
      gl2lds16(gA[s] + k0, lA + (size_t)(s * 256 + tid) * 8);
      gl2lds16(gB[s] + k0, lB + (size_t)(s * 256 + tid) * 8);
    }
    __syncthreads();
    frag_ab af[4], bfr[4];
#pragma unroll
    for (int i = 0; i < 4; i++)
      af[i] = *(const frag_ab*)(lA + (size_t)(wm * 64 + i * 16 + mr) * 32 + q * 8);
#pragma unroll
    for (int j = 0; j < 4; j++)
      bfr[j] = *(const frag_ab*)(lB + (size_t)(wn * 64 + j * 16 + mr) * 32 + q * 8);
#pragma unroll
    for (int i = 0; i < 4; i++)
#pragma unroll
      for (int j = 0; j < 4; j++)
        acc[i][j] = __builtin_amdgcn_mfma_f32_16x16x32_bf16(af[i], bfr[j], acc[i][j], 0, 0, 0);
    __syncthreads();
  }

  int col = lane & 15;
#pragma unroll
  for (int i = 0; i < 4; i++) {
#pragma unroll
    for (int j = 0; j < 4; j++) {
#pragma unroll
      for (int r = 0; r < 4; r++) {
        int mg = m0 + wm * 64 + i * 16 + q * 4 + r;
        if (mg < cnt) {
          int ng = n0 + wn * 64 + j * 16 + col;
          y[(size_t)(off + mg) * E_DIM + ng] = f2bf(acc[i][j][r]);
        }
      }
    }
  }
}

// ---- combine: out[t] = 0.5*(y[slot0] + y[slot1] + b2[e0] + b2[e1]) ----
__global__ __launch_bounds__(256) void k_combine(const u16* __restrict__ y,
                                                 const float* __restrict__ b2,
                                                 const int* __restrict__ t2,
                                                 float* __restrict__ out) {
  int t = blockIdx.x;
  int c = threadIdx.x * 4;
  int v0 = t2[t * 2 + 0], v1 = t2[t * 2 + 1];
  int e0 = v0 & 7, s0 = v0 >> 3;
  int e1 = v1 & 7, s1 = v1 >> 3;
  ushort4 a = *(const ushort4*)(y + (size_t)s0 * E_DIM + c);
  ushort4 b = *(const ushort4*)(y + (size_t)s1 * E_DIM + c);
  float4 p0 = *(const float4*)(b2 + (size_t)e0 * E_DIM + c);
  float4 p1 = *(const float4*)(b2 + (size_t)e1 * E_DIM + c);
  float4 o;
  o.x = 0.5f * (bf2f(a.x) + bf2f(b.x) + p0.x + p1.x);
  o.y = 0.5f * (bf2f(a.y) + bf2f(b.y) + p0.y + p1.y);
  o.z = 0.5f * (bf2f(a.z) + bf2f(b.z) + p0.z + p1.z);
  o.w = 0.5f * (bf2f(a.w) + bf2f(b.w) + p0.w + p1.w);
  *(float4*)(out + (size_t)t * E_DIM + c) = o;
}

extern "C" void kernel_launch(void* const* d_in, const int* in_sizes, int n_in,
                              void* d_out, int out_size, void* d_ws, size_t ws_size,
                              hipStream_t stream) {
  (void)in_sizes; (void)n_in; (void)out_size; (void)ws_size;
  const float* x  = (const float*)d_in[0];
  const float* Wr = (const float*)d_in[1];
  const float* br = (const float*)d_in[2];
  const float* W1 = (const float*)d_in[3];
  const float* b1 = (const float*)d_in[4];
  const float* W2 = (const float*)d_in[5];
  const float* b2 = (const float*)d_in[6];
  float* out = (float*)d_out;
  char* ws = (char*)d_ws;

  int* meta  = (int*)ws;                  // counts@0, cursors@+16 ints
  int* t2    = (int*)(ws + O_T2);
  int* clist = (int*)(ws + O_CLIST);
  u16* xb    = (u16*)(ws + O_XB);
  u16* w1t   = (u16*)(ws + O_W1T);
  u16* w2t   = (u16*)(ws + O_W2T);
  u16* hb    = (u16*)(ws + O_HB);
  u16* y     = (u16*)(ws + O_Y);          // overlays xb+w1t (dead after gemm1)

  hipMemsetAsync(ws, 0, 128, stream);     // zero counts + cursors

  k_prep<<<dim3(8192), 256, 0, stream>>>(x, Wr, br, W1, W2, out, xb, w1t, w2t, t2, meta);
  k_fill<<<dim3(T_TOK / 256), 256, 0, stream>>>(t2, meta, meta + 16, clist);
  k_gemm1<<<dim3(64, H_DIM / 128, X_EXP), 256, 0, stream>>>(xb, w1t, b1, hb, meta, clist);
  k_gemm2<<<dim3(64, E_DIM / 128, X_EXP), 256, 0, stream>>>(hb, w2t, y, meta);
  k_combine<<<dim3(T_TOK), 256, 0, stream>>>(y, b2, t2, out);
}

// Round 6
// 490.987 us; speedup vs baseline: 1.6748x; 1.1755x over previous
//
#include <hip/hip_runtime.h>
#include <hip/hip_bf16.h>
#include <math.h>

// MoE: B=8,N=1024,E=1024,H=1536,X=8,K=2. Routed (top-2 only) bf16 MFMA impl.
// R6: GEMMs: BK=64 (half the barrier drains), XCD-aware grid (expert = bid&7,
//     n0-fastest => per-XCD L2 holds one expert's B-slab), XOR col swizzle on
//     the staging source side => conflict-free ds_read_b128.
#define T_TOK 8192
#define E_DIM 1024
#define H_DIM 1536
#define X_EXP 8

typedef unsigned short u16;
typedef unsigned int u32;

typedef __attribute__((ext_vector_type(8))) short frag_ab;   // 8 bf16 (4 VGPRs)
typedef __attribute__((ext_vector_type(4))) float frag_cd;   // 4 fp32 acc

__device__ __forceinline__ u16 f2bf(float f) {
  u32 u = __float_as_uint(f);
  u32 r = u + 0x7fffu + ((u >> 16) & 1u);   // round-to-nearest-even
  return (u16)(r >> 16);
}
__device__ __forceinline__ float bf2f(u16 h) {
  return __uint_as_float(((u32)h) << 16);
}

__device__ __forceinline__ void gl2lds16(const u16* g, u16* l) {
  // async global->LDS, 16B per lane; LDS dst must be wave-uniform base + lane*16
  __builtin_amdgcn_global_load_lds((const __attribute__((address_space(1))) void*)g,
                                   (__attribute__((address_space(3))) void*)l,
                                   16, 0, 0);
}

// ---- workspace layout (bytes) ----
static const size_t O_T2    = 4096;                                   // T*2 ints
static const size_t O_CLIST = O_T2 + (size_t)T_TOK * 2 * 4;           // 69632
static const size_t O_XB    = O_CLIST + (size_t)T_TOK * 2 * 4;        // 135168
static const size_t O_W1T   = O_XB + (size_t)T_TOK * E_DIM * 2;       // 16912384
static const size_t O_W2T   = O_W1T + (size_t)X_EXP * E_DIM * H_DIM * 2; // 42078208
static const size_t O_HB    = O_W2T + (size_t)X_EXP * E_DIM * H_DIM * 2; // 67244032
// end = 117575680 bytes (~112 MiB). y overlays xb+w1t (dead after gemm1).
static const size_t O_Y     = O_XB;

// ---- fused prep (unchanged from R5) ----
__global__ __launch_bounds__(256) void k_prep(const float* __restrict__ x,
                                              const float* __restrict__ Wr,
                                              const float* __restrict__ br,
                                              const float* __restrict__ W1,
                                              const float* __restrict__ W2,
                                              float* __restrict__ out,
                                              u16* __restrict__ xb,
                                              u16* __restrict__ w1t,
                                              u16* __restrict__ w2t,
                                              int* __restrict__ t2,
                                              int* __restrict__ counts) {
  __shared__ union {
    float tile[64][65];
    float red[4][4][8];
  } sm;
  int blk = blockIdx.x;
  int tid = threadIdx.x;

  if (blk < 2048) {
    float4 wq[8];
    {
      const float4* wr4 = (const float4*)Wr + (size_t)tid * 8;
#pragma unroll
      for (int j = 0; j < 8; j++) wq[j] = wr4[j];
    }
    float acc[4][8];
#pragma unroll
    for (int it = 0; it < 4; it++)
#pragma unroll
      for (int e = 0; e < 8; e++) acc[it][e] = 0.f;

#pragma unroll
    for (int it = 0; it < 4; it++) {
      size_t base = (size_t)blk * 4096 + it * 1024 + tid * 4;
      float4 v = *(const float4*)(x + base);
      ushort4 o;
      o.x = f2bf(v.x); o.y = f2bf(v.y); o.z = f2bf(v.z); o.w = f2bf(v.w);
      *(ushort4*)(xb + base) = o;
      float xv[4] = {v.x, v.y, v.z, v.w};
#pragma unroll
      for (int j = 0; j < 4; j++) {
#pragma unroll
        for (int e = 0; e < 8; e++) {
          float4 q = wq[j * 2 + (e >> 2)];
          float wv = (e & 3) == 0 ? q.x : (e & 3) == 1 ? q.y : (e & 3) == 2 ? q.z : q.w;
          acc[it][e] += xv[j] * wv;
        }
      }
    }
#pragma unroll
    for (int off = 32; off; off >>= 1)
#pragma unroll
      for (int it = 0; it < 4; it++)
#pragma unroll
        for (int e = 0; e < 8; e++)
          acc[it][e] += __shfl_down(acc[it][e], off);
    int lane = tid & 63, wave = tid >> 6;
    if (lane == 0) {
#pragma unroll
      for (int it = 0; it < 4; it++)
#pragma unroll
        for (int e = 0; e < 8; e++) sm.red[wave][it][e] = acc[it][e];
    }
    __syncthreads();
    if (tid < 4) {
      int t = blk * 4 + tid;
      float lg[8];
#pragma unroll
      for (int e = 0; e < 8; e++)
        lg[e] = sm.red[0][tid][e] + sm.red[1][tid][e] + sm.red[2][tid][e] + sm.red[3][tid][e] + br[e];
      int i0 = 0; float v0 = lg[0];
#pragma unroll
      for (int e = 1; e < 8; e++) if (lg[e] > v0) { v0 = lg[e]; i0 = e; }
      int i1 = -1; float v1 = -3.4e38f;
#pragma unroll
      for (int e = 0; e < 8; e++) if (e != i0 && lg[e] > v1) { v1 = lg[e]; i1 = e; }
      out[(size_t)T_TOK * E_DIM + (size_t)t * 2 + 0] = (float)i0;
      out[(size_t)T_TOK * E_DIM + (size_t)t * 2 + 1] = (float)i1;
      t2[t * 2 + 0] = i0;
      t2[t * 2 + 1] = i1;
      atomicAdd(&counts[i0], 1);
      atomicAdd(&counts[i1], 1);
    }
  } else {
    const float* src; u16* dst; int R, C, bx, by, e;
    if (blk < 5120) {
      int l = blk - 2048;           // W1: R=E=1024, C=H=1536, grid (24,16,8)
      bx = l % 24; by = (l / 24) % 16; e = l / 384;
      R = E_DIM; C = H_DIM;
      src = W1 + (size_t)e * R * C; dst = w1t + (size_t)e * R * C;
    } else {
      int l = blk - 5120;           // W2: R=H=1536, C=E=1024, grid (16,24,8)
      bx = l % 16; by = (l / 16) % 24; e = l / 384;
      R = H_DIM; C = E_DIM;
      src = W2 + (size_t)e * R * C; dst = w2t + (size_t)e * R * C;
    }
    int c0 = bx * 64, r0 = by * 64;
    int tc = tid & 15, tr = tid >> 4;
#pragma unroll
    for (int i = 0; i < 4; i++) {
      int rr = tr + i * 16;
      float4 v = *(const float4*)(src + (size_t)(r0 + rr) * C + c0 + tc * 4);
      sm.tile[rr][tc * 4 + 0] = v.x;
      sm.tile[rr][tc * 4 + 1] = v.y;
      sm.tile[rr][tc * 4 + 2] = v.z;
      sm.tile[rr][tc * 4 + 3] = v.w;
    }
    __syncthreads();
#pragma unroll
    for (int i = 0; i < 4; i++) {
      int hh = tr + i * 16;
      ushort4 o;
      o.x = f2bf(sm.tile[tc * 4 + 0][hh]);
      o.y = f2bf(sm.tile[tc * 4 + 1][hh]);
      o.z = f2bf(sm.tile[tc * 4 + 2][hh]);
      o.w = f2bf(sm.tile[tc * 4 + 3][hh]);
      *(ushort4*)(dst + (size_t)(c0 + hh) * R + r0 + tc * 4) = o;
    }
  }
}

// fills clist and packs compact slot into t2: t2[t*2+k] = e | (slot<<3)
__global__ __launch_bounds__(256) void k_fill(int* __restrict__ t2,
                                              const int* __restrict__ counts,
                                              int* __restrict__ curs,
                                              int* __restrict__ clist) {
  int offs[8];
  {
    int run = 0;
#pragma unroll
    for (int e = 0; e < 8; e++) { offs[e] = run; run += counts[e]; }
  }
  int t = blockIdx.x * 256 + threadIdx.x;
#pragma unroll
  for (int k = 0; k < 2; k++) {
    int e = t2[t * 2 + k] & 7;
    int p = atomicAdd(&curs[e], 1);
    int slot = offs[e] + p;
    clist[slot] = t;
    t2[t * 2 + k] = e | (slot << 3);
  }
}

// ---- GEMM1: h = gelu(gather(x) @ W1[e] + b1[e]) -> hb (bf16, compact rows) ----
// Flat grid 6144: e = bid&7 (XCD-aware), slot = bid>>3; n0-fastest within m0.
// BK=64; LDS rows 64 u16 with XOR-8 column-group swizzle on the source side.
__global__ __launch_bounds__(256) void k_gemm1(const u16* __restrict__ xb,
                                               const u16* __restrict__ w1t,
                                               const float* __restrict__ b1,
                                               u16* __restrict__ hb,
                                               const int* __restrict__ counts,
                                               const int* __restrict__ clist) {
  int bid = blockIdx.x;
  int e = bid & 7;
  int slot = bid >> 3;                    // 0..767
  int cnt = counts[e];
  int m0 = (slot / 12) * 128;
  if (m0 >= cnt) return;
  int n0 = (slot % 12) * 128;
  int off = 0;
  for (int j = 0; j < 8; j++) off += (j < e) ? counts[j] : 0;
  int tid = threadIdx.x;
  int lane = tid & 63, wave = tid >> 6;
  int wm = wave >> 1, wn = wave & 1;

  __shared__ __align__(16) u16 lA[128 * 64];   // 16 KB
  __shared__ __align__(16) u16 lB[128 * 64];   // 16 KB

  const u16* gA[4];
  const u16* gB[4];
#pragma unroll
  for (int s = 0; s < 4; s++) {
    int idx = s * 256 + tid;               // 0..1023
    int r = idx >> 3;                      // 0..127
    int cg = (idx & 7) ^ (r & 7);          // swizzled global col group
    int mrow = m0 + r; if (mrow >= cnt) mrow = cnt - 1;
    int tok = clist[off + mrow];
    gA[s] = xb + (size_t)tok * E_DIM + cg * 8;
    gB[s] = w1t + (size_t)e * H_DIM * E_DIM + (size_t)(n0 + r) * E_DIM + cg * 8;
  }

  frag_cd acc[4][4] = {};
  int q = lane >> 4, mr = lane & 15;
  int mr7 = mr & 7;

  for (int k0 = 0; k0 < E_DIM; k0 += 64) {
#pragma unroll
    for (int s = 0; s < 4; s++) {
      gl2lds16(gA[s] + k0, lA + (size_t)(s * 256 + tid) * 8);
      gl2lds16(gB[s] + k0, lB + (size_t)(s * 256 + tid) * 8);
    }
    __syncthreads();
#pragma unroll
    for (int ks = 0; ks < 2; ks++) {
      int g = (q + 4 * ks) ^ mr7;          // swizzled col group for this lane
      frag_ab af[4], bfr[4];
#pragma unroll
      for (int i = 0; i < 4; i++)
        af[i] = *(const frag_ab*)(lA + (size_t)(wm * 64 + i * 16 + mr) * 64 + g * 8);
#pragma unroll
      for (int j = 0; j < 4; j++)
        bfr[j] = *(const frag_ab*)(lB + (size_t)(wn * 64 + j * 16 + mr) * 64 + g * 8);
#pragma unroll
      for (int i = 0; i < 4; i++)
#pragma unroll
        for (int j = 0; j < 4; j++)
          acc[i][j] = __builtin_amdgcn_mfma_f32_16x16x32_bf16(af[i], bfr[j], acc[i][j], 0, 0, 0);
    }
    __syncthreads();
  }

  int col = lane & 15;
#pragma unroll
  for (int i = 0; i < 4; i++) {
#pragma unroll
    for (int j = 0; j < 4; j++) {
#pragma unroll
      for (int r = 0; r < 4; r++) {
        int mg = m0 + wm * 64 + i * 16 + q * 4 + r;
        if (mg < cnt) {
          int ng = n0 + wn * 64 + j * 16 + col;
          float v = acc[i][j][r] + b1[e * H_DIM + ng];
          // tanh-GELU via sigmoid: v * sigma(1.5957691v + 0.0713548v^3)
          float z = v * (1.5957691216f + 0.0713548162f * v * v);
          v = v / (1.0f + __expf(-z));
          hb[(size_t)(off + mg) * H_DIM + ng] = f2bf(v);
        }
      }
    }
  }
}

// ---- GEMM2: y[slot] = hb @ W2[e]  (compact bf16 store, bias/mean in combine) ----
__global__ __launch_bounds__(256) void k_gemm2(const u16* __restrict__ hb,
                                               const u16* __restrict__ w2t,
                                               u16* __restrict__ y,
                                               const int* __restrict__ counts) {
  int bid = blockIdx.x;
  int e = bid & 7;
  int slot = bid >> 3;                    // 0..511
  int cnt = counts[e];
  int m0 = (slot / 8) * 128;
  if (m0 >= cnt) return;
  int n0 = (slot % 8) * 128;
  int off = 0;
  for (int j = 0; j < 8; j++) off += (j < e) ? counts[j] : 0;
  int tid = threadIdx.x;
  int lane = tid & 63, wave = tid >> 6;
  int wm = wave >> 1, wn = wave & 1;

  __shared__ __align__(16) u16 lA[128 * 64];
  __shared__ __align__(16) u16 lB[128 * 64];

  const u16* gA[4];
  const u16* gB[4];
#pragma unroll
  for (int s = 0; s < 4; s++) {
    int idx = s * 256 + tid;
    int r = idx >> 3;
    int cg = (idx & 7) ^ (r & 7);
    int mrow = m0 + r; if (mrow >= cnt) mrow = cnt - 1;
    gA[s] = hb + (size_t)(off + mrow) * H_DIM + cg * 8;
    gB[s] = w2t + (size_t)e * E_DIM * H_DIM + (size_t)(n0 + r) * H_DIM + cg * 8;
  }

  frag_cd acc[4][4] = {};
  int q = lane >> 4, mr = lane & 15;
  int mr7 = mr & 7;

  for (int k0 = 0; k0 < H_DIM; k0 += 64) {
#pragma unroll
    for (int s = 0; s < 4; s++) {
      gl2lds16(gA[s] + k0, lA + (size_t)(s * 256 + tid) * 8);
      gl2lds16(gB[s] + k0, lB + (size_t)(s * 256 + tid) * 8);
    }
    __syncthreads();
#pragma unroll
    for (int ks = 0; ks < 2; ks++) {
      int g = (q + 4 * ks) ^ mr7;
      frag_ab af[4], bfr[4];
#pragma unroll
      for (int i = 0; i < 4; i++)
        af[i] = *(const frag_ab*)(lA + (size_t)(wm * 64 + i * 16 + mr) * 64 + g * 8);
#pragma unroll
      for (int j = 0; j < 4; j++)
        bfr[j] = *(const frag_ab*)(lB + (size_t)(wn * 64 + j * 16 + mr) * 64 + g * 8);
#pragma unroll
      for (int i = 0; i < 4; i++)
#pragma unroll
        for (int j = 0; j < 4; j++)
          acc[i][j] = __builtin_amdgcn_mfma_f32_16x16x32_bf16(af[i], bfr[j], acc[i][j], 0, 0, 0);
    }
    __syncthreads();
  }

  int col = lane & 15;
#pragma unroll
  for (int i = 0; i < 4; i++) {
#pragma unroll
    for (int j = 0; j < 4; j++) {
#pragma unroll
      for (int r = 0; r < 4; r++) {
        int mg = m0 + wm * 64 + i * 16 + q * 4 + r;
        if (mg < cnt) {
          int ng = n0 + wn * 64 + j * 16 + col;
          y[(size_t)(off + mg) * E_DIM + ng] = f2bf(acc[i][j][r]);
        }
      }
    }
  }
}

// ---- combine: out[t] = 0.5*(y[slot0] + y[slot1] + b2[e0] + b2[e1]) ----
__global__ __launch_bounds__(256) void k_combine(const u16* __restrict__ y,
                                                 const float* __restrict__ b2,
                                                 const int* __restrict__ t2,
                                                 float* __restrict__ out) {
  int t = blockIdx.x;
  int c = threadIdx.x * 4;
  int v0 = t2[t * 2 + 0], v1 = t2[t * 2 + 1];
  int e0 = v0 & 7, s0 = v0 >> 3;
  int e1 = v1 & 7, s1 = v1 >> 3;
  ushort4 a = *(const ushort4*)(y + (size_t)s0 * E_DIM + c);
  ushort4 b = *(const ushort4*)(y + (size_t)s1 * E_DIM + c);
  float4 p0 = *(const float4*)(b2 + (size_t)e0 * E_DIM + c);
  float4 p1 = *(const float4*)(b2 + (size_t)e1 * E_DIM + c);
  float4 o;
  o.x = 0.5f * (bf2f(a.x) + bf2f(b.x) + p0.x + p1.x);
  o.y = 0.5f * (bf2f(a.y) + bf2f(b.y) + p0.y + p1.y);
  o.z = 0.5f * (bf2f(a.z) + bf2f(b.z) + p0.z + p1.z);
  o.w = 0.5f * (bf2f(a.w) + bf2f(b.w) + p0.w + p1.w);
  *(float4*)(out + (size_t)t * E_DIM + c) = o;
}

extern "C" void kernel_launch(void* const* d_in, const int* in_sizes, int n_in,
                              void* d_out, int out_size, void* d_ws, size_t ws_size,
                              hipStream_t stream) {
  (void)in_sizes; (void)n_in; (void)out_size; (void)ws_size;
  const float* x  = (const float*)d_in[0];
  const float* Wr = (const float*)d_in[1];
  const float* br = (const float*)d_in[2];
  const float* W1 = (const float*)d_in[3];
  const float* b1 = (const float*)d_in[4];
  const float* W2 = (const float*)d_in[5];
  const float* b2 = (const float*)d_in[6];
  float* out = (float*)d_out;
  char* ws = (char*)d_ws;

  int* meta  = (int*)ws;                  // counts@0, cursors@+16 ints
  int* t2    = (int*)(ws + O_T2);
  int* clist = (int*)(ws + O_CLIST);
  u16* xb    = (u16*)(ws + O_XB);
  u16* w1t   = (u16*)(ws + O_W1T);
  u16* w2t   = (u16*)(ws + O_W2T);
  u16* hb    = (u16*)(ws + O_HB);
  u16* y     = (u16*)(ws + O_Y);          // overlays xb+w1t (dead after gemm1)

  hipMemsetAsync(ws, 0, 128, stream);     // zero counts + cursors

  k_prep<<<dim3(8192), 256, 0, stream>>>(x, Wr, br, W1, W2, out, xb, w1t, w2t, t2, meta);
  k_fill<<<dim3(T_TOK / 256), 256, 0, stream>>>(t2, meta, meta + 16, clist);
  k_gemm1<<<dim3(8 * 64 * 12), 256, 0, stream>>>(xb, w1t, b1, hb, meta, clist);
  k_gemm2<<<dim3(8 * 64 * 8), 256, 0, stream>>>(hb, w2t, y, meta);
  k_combine<<<dim3(T_TOK), 256, 0, stream>>>(y, b2, t2, out);
}